// Round 2
// baseline (415.705 us; speedup 1.0000x reference)
//
#include <hip/hip_runtime.h>
#include <hip/hip_bf16.h>

namespace {
constexpr int B = 64;
constexpr int L = 1024;
constexpr int D = 64;
constexpr float INV_TEMP = 0.125f;  // 1/8

typedef float f32x4 __attribute__((ext_vector_type(4)));
typedef __bf16 bf16x8 __attribute__((ext_vector_type(8)));
typedef __bf16 bf16x4 __attribute__((ext_vector_type(4)));

__device__ inline __bf16 f2bf(float f) {
  unsigned u = __builtin_bit_cast(unsigned, f);
  u = (u + 0x7FFFu + ((u >> 16) & 1u)) >> 16;  // RNE, inputs are finite
  unsigned short s = (unsigned short)u;
  return __builtin_bit_cast(__bf16, s);
}

__device__ inline bf16x8 cvt8(const float* __restrict__ p) {
  f32x4 a = *reinterpret_cast<const f32x4*>(p);
  f32x4 b = *reinterpret_cast<const f32x4*>(p + 4);
  bf16x8 r;
  r[0] = f2bf(a[0]); r[1] = f2bf(a[1]); r[2] = f2bf(a[2]); r[3] = f2bf(a[3]);
  r[4] = f2bf(b[0]); r[5] = f2bf(b[1]); r[6] = f2bf(b[2]); r[7] = f2bf(b[3]);
  return r;
}
}  // namespace

// One block = 64 keys (4 waves x 16 keys), one batch. Loop over all 1024 q
// in steps of 32. GEMM1: S = Q K^T (16x16x32 MFMA, A=Q rows, B=K rows).
// Elementwise: p = mask ? 0 : sigmoid(S/8 * gate); store attn; stage P^T in
// LDS (bf16, [k][q] layout, padded). GEMM2: O[k][d] += P^T V via MFMA.
__global__ __launch_bounds__(256)
void gated_attn_kernel(const float* __restrict__ qp,
                       const float* __restrict__ kp,
                       const float* __restrict__ vp,
                       const int* __restrict__ mask,   // bool -> int32 on device
                       const float* __restrict__ gate,
                       float* __restrict__ out_o,
                       float* __restrict__ out_attn) {
  constexpr int QPAD = 40;  // 32 q + pad; 80B rows keep b128 reads 16B-aligned
  __shared__ __bf16 plds[4][16 * QPAD];

  const int wave = threadIdx.x >> 6;
  const int lane = threadIdx.x & 63;
  const int col  = lane & 15;   // N-index of MFMA fragments
  const int lgrp = lane >> 4;   // quarter-wave id

  const int b = blockIdx.y;
  const int kbase = blockIdx.x * 64 + wave * 16;

  // K fragments (B operand of GEMM1) are loop-invariant for this wave.
  const float* krow = kp + ((size_t)(b * L + kbase + col)) * D;
  const bf16x8 kf0 = cvt8(krow + 0  + lgrp * 8);
  const bf16x8 kf1 = cvt8(krow + 32 + lgrp * 8);

  f32x4 acc[4] = {};  // O: rows = 16 keys, cols = 4 x 16 d

  __bf16* myp = &plds[wave][0];

  for (int qb = 0; qb < L; qb += 32) {
    // ---- GEMM1: S[32 q][16 k] ----
    f32x4 s[2];
#pragma unroll
    for (int r = 0; r < 2; ++r) {
      const float* qrow = qp + ((size_t)(b * L + qb + r * 16 + col)) * D;
      f32x4 c = {};
      c = __builtin_amdgcn_mfma_f32_16x16x32_bf16(cvt8(qrow + 0  + lgrp * 8), kf0, c, 0, 0, 0);
      c = __builtin_amdgcn_mfma_f32_16x16x32_bf16(cvt8(qrow + 32 + lgrp * 8), kf1, c, 0, 0, 0);
      s[r] = c;
    }

    // ---- gate * mask * sigmoid; write attn; stage P in LDS as [k][q] ----
#pragma unroll
    for (int r = 0; r < 2; ++r) {
      const int q0 = qb + r * 16 + lgrp * 4;
      bf16x4 pk;
#pragma unroll
      for (int i = 0; i < 4; ++i) {
        const size_t idx = ((size_t)(b * L + q0 + i)) * L + kbase + col;
        const float x = s[r][i] * INV_TEMP * gate[idx];
        const float p = mask[idx] ? 0.0f : 1.0f / (1.0f + __expf(-x));
        out_attn[idx] = p;
        pk[i] = f2bf(p);
      }
      *reinterpret_cast<bf16x4*>(myp + col * QPAD + r * 16 + lgrp * 4) = pk;
    }

    __syncthreads();  // order LDS write -> read (lgkmcnt fence)

    // A operand of GEMM2: P^T[k=col][q = lgrp*8 + 0..7]
    const bf16x8 a2 = *reinterpret_cast<const bf16x8*>(myp + col * QPAD + lgrp * 8);

    // ---- GEMM2: O[16 k][64 d] += P^T[16 k][32 q] * V[32 q][64 d] ----
    const float* vrow = vp + ((size_t)(b * L + qb + lgrp * 8)) * D + col;
#pragma unroll
    for (int t = 0; t < 4; ++t) {
      bf16x8 b2;
#pragma unroll
      for (int j = 0; j < 8; ++j) {
        b2[j] = f2bf(vrow[(size_t)j * D + t * 16]);
      }
      acc[t] = __builtin_amdgcn_mfma_f32_16x16x32_bf16(a2, b2, acc[t], 0, 0, 0);
    }
  }

  // ---- epilogue: O[b][k][d] ----
#pragma unroll
  for (int t = 0; t < 4; ++t) {
#pragma unroll
    for (int i = 0; i < 4; ++i) {
      const int kr = kbase + lgrp * 4 + i;
      out_o[((size_t)(b * L + kr)) * D + t * 16 + col] = acc[t][i];
    }
  }
}

extern "C" void kernel_launch(void* const* d_in, const int* in_sizes, int n_in,
                              void* d_out, int out_size, void* d_ws, size_t ws_size,
                              hipStream_t stream) {
  const float* q = (const float*)d_in[0];
  const float* k = (const float*)d_in[1];
  const float* v = (const float*)d_in[2];
  const int* mask = (const int*)d_in[3];
  const float* gate = (const float*)d_in[4];

  float* out_o = (float*)d_out;                       // [B, L, D]
  float* out_attn = out_o + (size_t)B * L * D;        // [B, L, L]

  dim3 grid(L / 64, B);
  gated_attn_kernel<<<grid, dim3(256), 0, stream>>>(q, k, v, mask, gate,
                                                    out_o, out_attn);
}

// Round 3
// 260.514 us; speedup vs baseline: 1.5957x; 1.5957x over previous
//
#include <hip/hip_runtime.h>
#include <hip/hip_bf16.h>

namespace {
constexpr int B = 64;
constexpr int L = 1024;
constexpr int D = 64;
constexpr float INV_TEMP = 0.125f;  // 1/8
constexpr int QSTEP = 32;
constexpr int VSTRIDE = 40;  // bf16/row: 80 B rows -> 16B-aligned b128, spread banks
constexpr int PSTRIDE = 40;

typedef float f32x4 __attribute__((ext_vector_type(4)));
typedef int   i32x4 __attribute__((ext_vector_type(4)));
typedef __bf16 bf16x8 __attribute__((ext_vector_type(8)));
typedef unsigned int u32;

__device__ inline bf16x8 cvt8(const float* __restrict__ p) {
  f32x4 a = *reinterpret_cast<const f32x4*>(p);
  f32x4 b = *reinterpret_cast<const f32x4*>(p + 4);
  bf16x8 r;
  r[0] = (__bf16)a[0]; r[1] = (__bf16)a[1]; r[2] = (__bf16)a[2]; r[3] = (__bf16)a[3];
  r[4] = (__bf16)b[0]; r[5] = (__bf16)b[1]; r[6] = (__bf16)b[2]; r[7] = (__bf16)b[3];
  return r;
}
}  // namespace

// Block = 64 keys (4 waves x 16 k), one batch. S^T layout: GEMM1 computes
// S^T[k][q] = mfma(A=K rows, B=Q rows) so each lane owns 4 consecutive k for
// one q -> float4 gate/mask/attn. V tile staged block-wide in LDS (VT[d][q],
// double-buffered); P^T per-wave in LDS. gate/mask/V for step i+1 prefetched
// after the barrier, consumed before the next one (hides HBM latency).
__global__ __launch_bounds__(256)
void gated_attn_kernel(const float* __restrict__ qp,
                       const float* __restrict__ kp,
                       const float* __restrict__ vp,
                       const int* __restrict__ mask,   // bool -> int32
                       const float* __restrict__ gate,
                       float* __restrict__ out_o,
                       float* __restrict__ out_attn) {
  __shared__ __bf16 vt[2][D * VSTRIDE];       // 2 x 5120 B
  __shared__ __bf16 pt[4][16 * PSTRIDE];      // 4 x 1280 B (per-wave private)

  const int tid  = threadIdx.x;
  const int wave = tid >> 6;
  const int lane = tid & 63;
  const int col  = lane & 15;
  const int lgrp = lane >> 4;

  const int b = blockIdx.y;
  const int kbase = blockIdx.x * 64 + wave * 16;

  // A-operand K fragments (loop-invariant): K[kbase+col][lgrp*8+j (+32)]
  const float* krow = kp + ((size_t)(b * L + kbase + col)) * D + lgrp * 8;
  const bf16x8 kf0 = cvt8(krow);
  const bf16x8 kf1 = cvt8(krow + 32);

  f32x4 acc[4] = {};  // O[k = kbase+lgrp*4+i][d = t*16+col]

  // cooperative V staging: thread handles q-pair (2*vq, 2*vq+1), d = vd..vd+3
  const int vq = tid >> 4;
  const int vd = (tid & 15) * 4;

  f32x4 g[2]; i32x4 m[2]; f32x4 va, vb;

  auto load_gm = [&](int qb) {
#pragma unroll
    for (int sub = 0; sub < 2; ++sub) {
      const size_t idx =
          ((size_t)(b * L + qb + sub * 16 + col)) * L + kbase + lgrp * 4;
      g[sub] = *reinterpret_cast<const f32x4*>(gate + idx);
      m[sub] = *reinterpret_cast<const i32x4*>(mask + idx);
    }
  };
  auto load_v = [&](int qb) {
    const float* vr = vp + ((size_t)(b * L + qb + 2 * vq)) * D + vd;
    va = *reinterpret_cast<const f32x4*>(vr);
    vb = *reinterpret_cast<const f32x4*>(vr + D);
  };

  load_gm(0);
  load_v(0);

  for (int qb = 0; qb < L; qb += QSTEP) {
    const int buf = (qb >> 5) & 1;

    // ---- GEMM1: S^T[16k x 16q], 2 q-subtiles ----
    f32x4 s[2];
#pragma unroll
    for (int sub = 0; sub < 2; ++sub) {
      const float* qrow =
          qp + ((size_t)(b * L + qb + sub * 16 + col)) * D + lgrp * 8;
      f32x4 c = {};
      c = __builtin_amdgcn_mfma_f32_16x16x32_bf16(kf0, cvt8(qrow), c, 0, 0, 0);
      c = __builtin_amdgcn_mfma_f32_16x16x32_bf16(kf1, cvt8(qrow + 32), c, 0, 0, 0);
      s[sub] = c;
    }

    // ---- elementwise (prefetched gate/mask): attn float4 store, P^T -> LDS ----
    __bf16* myp = &pt[wave][0];
#pragma unroll
    for (int sub = 0; sub < 2; ++sub) {
      const size_t idx =
          ((size_t)(b * L + qb + sub * 16 + col)) * L + kbase + lgrp * 4;
      f32x4 p;
#pragma unroll
      for (int i = 0; i < 4; ++i) {
        const float x = s[sub][i] * INV_TEMP * g[sub][i];
        p[i] = m[sub][i] ? 0.0f : 1.0f / (1.0f + __expf(-x));
      }
      *reinterpret_cast<f32x4*>(out_attn + idx) = p;
#pragma unroll
      for (int i = 0; i < 4; ++i)
        myp[(lgrp * 4 + i) * PSTRIDE + sub * 16 + col] = (__bf16)p[i];
    }

    // ---- stage V^T (block-cooperative, prefetched): VT[d][q] bf16 ----
#pragma unroll
    for (int j = 0; j < 4; ++j) {
      const u32 pk =
          (u32)__builtin_bit_cast(unsigned short, (__bf16)va[j]) |
          ((u32)__builtin_bit_cast(unsigned short, (__bf16)vb[j]) << 16);
      *reinterpret_cast<u32*>(&vt[buf][(vd + j) * VSTRIDE + 2 * vq]) = pk;
    }

    __syncthreads();

    // A-frag for GEMM2: P^T[k=col][q=lgrp*8..+7]
    const bf16x8 pa =
        *reinterpret_cast<const bf16x8*>(&pt[wave][col * PSTRIDE + lgrp * 8]);

    // prefetch next step's HBM streams (consumed before the next barrier)
    if (qb + QSTEP < L) {
      load_gm(qb + QSTEP);
      load_v(qb + QSTEP);
    }

    // ---- GEMM2: O[16k][64d] += P^T[16k][32q] * V[32q][64d] ----
#pragma unroll
    for (int t = 0; t < 4; ++t) {
      const bf16x8 b2 = *reinterpret_cast<const bf16x8*>(
          &vt[buf][(t * 16 + col) * VSTRIDE + lgrp * 8]);
      acc[t] = __builtin_amdgcn_mfma_f32_16x16x32_bf16(pa, b2, acc[t], 0, 0, 0);
    }
  }

  // ---- epilogue ----
#pragma unroll
  for (int t = 0; t < 4; ++t) {
#pragma unroll
    for (int i = 0; i < 4; ++i) {
      const int kr = kbase + lgrp * 4 + i;
      out_o[((size_t)(b * L + kr)) * D + t * 16 + col] = acc[t][i];
    }
  }
}

extern "C" void kernel_launch(void* const* d_in, const int* in_sizes, int n_in,
                              void* d_out, int out_size, void* d_ws, size_t ws_size,
                              hipStream_t stream) {
  const float* q = (const float*)d_in[0];
  const float* k = (const float*)d_in[1];
  const float* v = (const float*)d_in[2];
  const int* mask = (const int*)d_in[3];
  const float* gate = (const float*)d_in[4];

  float* out_o = (float*)d_out;                 // [B, L, D]
  float* out_attn = out_o + (size_t)B * L * D;  // [B, L, L]

  dim3 grid(L / 64, B);
  gated_attn_kernel<<<grid, dim3(256), 0, stream>>>(q, k, v, mask, gate,
                                                    out_o, out_attn);
}